// Round 4
// baseline (526.632 us; speedup 1.0000x reference)
//
#include <hip/hip_runtime.h>
#include <math.h>

#define NPOS 16384
#define LBAG 30
#define HDIM 512

// ---------------------------------------------------------------------------
// Kernel A: EmbeddingBag(sum) + Hardtanh(0,1) for both sides.
// grid (NPOS, 2), block 128. Each block: one bag -> 512 clipped floats.
// ---------------------------------------------------------------------------
__global__ void bag_clip(const int* __restrict__ stm_idx,
                         const int* __restrict__ nstm_idx,
                         const float* __restrict__ emb,
                         float* __restrict__ x) {
    const int pos  = blockIdx.x;
    const int side = blockIdx.y;
    const int t    = threadIdx.x;                 // 0..127
    const int* bag = (side == 0 ? stm_idx : nstm_idx) + pos * LBAG;

    __shared__ int sidx[LBAG];
    if (t < LBAG) sidx[t] = bag[t];
    __syncthreads();

    const int col = t << 2;                       // 128 threads * float4 = 512
    float4 acc = make_float4(0.f, 0.f, 0.f, 0.f);
#pragma unroll
    for (int l = 0; l < LBAG; ++l) {
        const float4 v = *reinterpret_cast<const float4*>(
            emb + (size_t)sidx[l] * HDIM + col);
        acc.x += v.x; acc.y += v.y; acc.z += v.z; acc.w += v.w;
    }
    acc.x = fminf(fmaxf(acc.x, 0.f), 1.f);
    acc.y = fminf(fmaxf(acc.y, 0.f), 1.f);
    acc.z = fminf(fmaxf(acc.z, 0.f), 1.f);
    acc.w = fminf(fmaxf(acc.w, 0.f), 1.f);
    *reinterpret_cast<float4*>(x + (size_t)pos * 1024 + side * HDIM + col) = acc;
}

// ---------------------------------------------------------------------------
// Kernel B: fused MLP. Identical structure to round 3 EXCEPT:
//  - "#pragma unroll 1" on the kc loop. r2/r3 evidence: VGPR=256 + ~273 MB
//    scratch writes REGARDLESS of tile size -> the pressure came from LLVM
//    fully unrolling the 16-trip kc loop and hoisting/clustering all staged
//    global_load_dwordx4 across barriers. Blocking the unroll keeps only one
//    iteration's staging live (~20 float4).
//  - __launch_bounds__(128, 3) caps VGPR at ~170 as a spill guard.
// ---------------------------------------------------------------------------
#define KC 64
#define MT 32
#define SMEM_FLOATS (MT * 68 + 128 * 68)

__global__ __launch_bounds__(128, 3) void mlp(
    const float* __restrict__ x,     // [NPOS][1024]
    const float* __restrict__ W1,    // [128][1024]
    const float* __restrict__ b1,    // [128]
    const float* __restrict__ W2,    // [32][128]
    const float* __restrict__ b2,    // [32]
    const float* __restrict__ W3,    // [1][32]
    const float* __restrict__ b3,    // [1]
    float* __restrict__ out)         // [NPOS]
{
    __shared__ float smem[SMEM_FLOATS];
    float* xs  = smem;                 // [32][68]
    float* w1s = smem + MT * 68;       // [128][68]
    float* h1  = smem;                 // [32][132]
    float* w2  = smem + 32 * 132;      // [32][132]
    float* h2  = smem + 64 * 132;      // [32][33]

    const int t    = threadIdx.x;      // 0..127
    const int pblk = blockIdx.x * MT;
    const int pg   = t & 7;            // positions pg + 8*i, i=0..3
    const int og   = t >> 3;           // outputs  og + 16*j, j=0..7

    float acc[4][8];
#pragma unroll
    for (int i = 0; i < 4; ++i)
#pragma unroll
        for (int j = 0; j < 8; ++j) acc[i][j] = 0.f;

#pragma unroll 1
    for (int kc = 0; kc < 1024; kc += KC) {
        // stage x tile: 32 rows x 64 cols = 512 float4, 4 per thread
#pragma unroll
        for (int i = 0; i < 4; ++i) {
            int f = t + i * 128;
            int p = f >> 4, c4 = f & 15;
            float4 v = *reinterpret_cast<const float4*>(
                x + (size_t)(pblk + p) * 1024 + kc + c4 * 4);
            *reinterpret_cast<float4*>(&xs[p * 68 + c4 * 4]) = v;
        }
        // stage W1 tile: 128 rows x 64 cols = 2048 float4, 16 per thread
#pragma unroll
        for (int i = 0; i < 16; ++i) {
            int f = t + i * 128;
            int o = f >> 4, c4 = f & 15;
            float4 v = *reinterpret_cast<const float4*>(
                W1 + (size_t)o * 1024 + kc + c4 * 4);
            *reinterpret_cast<float4*>(&w1s[o * 68 + c4 * 4]) = v;
        }
        __syncthreads();
#pragma unroll
        for (int k4 = 0; k4 < 16; ++k4) {
            float4 a4[4], b4[8];
#pragma unroll
            for (int i = 0; i < 4; ++i)
                a4[i] = *reinterpret_cast<const float4*>(&xs[(pg + 8 * i) * 68 + k4 * 4]);
#pragma unroll
            for (int j = 0; j < 8; ++j)
                b4[j] = *reinterpret_cast<const float4*>(&w1s[(og + 16 * j) * 68 + k4 * 4]);
#pragma unroll
            for (int i = 0; i < 4; ++i)
#pragma unroll
                for (int j = 0; j < 8; ++j)
                    acc[i][j] += a4[i].x * b4[j].x + a4[i].y * b4[j].y +
                                 a4[i].z * b4[j].z + a4[i].w * b4[j].w;
        }
        __syncthreads();
    }

    // epilogue: bias + clip -> h1 (xs/w1s dead after last __syncthreads)
#pragma unroll
    for (int j = 0; j < 8; ++j) {
        int o = og + 16 * j;
        float bb = b1[o];
#pragma unroll
        for (int i = 0; i < 4; ++i) {
            float v = acc[i][j] + bb;
            v = fminf(fmaxf(v, 0.f), 1.f);
            h1[(pg + 8 * i) * 132 + o] = v;
        }
    }
    // stage W2 (32x128) into LDS: 4096 floats, 32 per thread
#pragma unroll
    for (int i = 0; i < 32; ++i) {
        int f = t + i * 128;
        int o = f >> 7, k = f & 127;
        w2[o * 132 + k] = W2[o * 128 + k];
    }
    __syncthreads();

    // layer2: 32 pos x 32 out. thread -> pos p2 = t>>2, 8 outputs each.
    {
        const int p2 = t >> 2;
        const int ob = (t & 3) * 8;
        float s[8];
#pragma unroll
        for (int jj = 0; jj < 8; ++jj) s[jj] = b2[ob + jj];
#pragma unroll
        for (int k4 = 0; k4 < 32; ++k4) {
            float4 h4 = *reinterpret_cast<const float4*>(&h1[p2 * 132 + k4 * 4]);
#pragma unroll
            for (int jj = 0; jj < 8; ++jj) {
                float4 w4 = *reinterpret_cast<const float4*>(&w2[(ob + jj) * 132 + k4 * 4]);
                s[jj] += h4.x * w4.x + h4.y * w4.y + h4.z * w4.z + h4.w * w4.w;
            }
        }
#pragma unroll
        for (int jj = 0; jj < 8; ++jj) {
            float v = fminf(fmaxf(s[jj], 0.f), 1.f);
            h2[p2 * 33 + ob + jj] = v;
        }
    }
    __syncthreads();

    // layer3 + tanh: one output per position
    if (t < MT) {
        float s = b3[0];
#pragma unroll
        for (int k = 0; k < 32; ++k) s += h2[t * 33 + k] * W3[k];
        out[pblk + t] = tanhf(s);
    }
}

// ---------------------------------------------------------------------------
extern "C" void kernel_launch(void* const* d_in, const int* in_sizes, int n_in,
                              void* d_out, int out_size, void* d_ws, size_t ws_size,
                              hipStream_t stream) {
    const int*   stm_idx  = (const int*)  d_in[0];
    const int*   nstm_idx = (const int*)  d_in[2];
    const float* emb      = (const float*)d_in[4];
    const float* W1       = (const float*)d_in[5];
    const float* b1       = (const float*)d_in[6];
    const float* W2       = (const float*)d_in[7];
    const float* b2       = (const float*)d_in[8];
    const float* W3       = (const float*)d_in[9];
    const float* b3       = (const float*)d_in[10];
    float*       out      = (float*)d_out;
    float*       x        = (float*)d_ws;        // NPOS*1024 fp32 = 64 MB

    dim3 gA(NPOS, 2);
    bag_clip<<<gA, 128, 0, stream>>>(stm_idx, nstm_idx, emb, x);

    mlp<<<NPOS / MT, 128, 0, stream>>>(x, W1, b1, W2, b2, W3, b3, out);
}

// Round 5
// 158.958 us; speedup vs baseline: 3.3130x; 3.3130x over previous
//
#include <hip/hip_runtime.h>
#include <math.h>

#define NPOS  16384
#define LBAG  30
#define NFEAT 40960
#define HDIM  512          // per side
#define MT    32           // positions per block

typedef short bf16x8 __attribute__((ext_vector_type(8)));  // 8 bf16 (guide §3 frag type)
typedef float f32x4  __attribute__((ext_vector_type(4)));

__device__ __forceinline__ unsigned int f2bf(float f) {
    // round-to-nearest-even f32 -> bf16 bits (finite values only)
    unsigned int u = __float_as_uint(f);
    return (u + 0x7fffu + ((u >> 16) & 1u)) >> 16;
}
__device__ __forceinline__ float clip01(float v) { return fminf(fmaxf(v, 0.f), 1.f); }

// ---------------------------------------------------------------------------
// Prep 1: emb fp32 -> bf16 (pairs packed in uint). 84MB read + 42MB write.
// ---------------------------------------------------------------------------
__global__ __launch_bounds__(256) void cvt_emb(const float* __restrict__ src,
                                               unsigned int* __restrict__ dst) {
    const int nchunk = NFEAT * HDIM / 8;             // 2,621,440 chunks of 8 floats
    int c = blockIdx.x * 256 + threadIdx.x;
    const int stride = gridDim.x * 256;
    for (; c < nchunk; c += stride) {
        float4 f0 = ((const float4*)src)[(size_t)c * 2];
        float4 f1 = ((const float4*)src)[(size_t)c * 2 + 1];
        uint4 o;
        o.x = f2bf(f0.x) | (f2bf(f0.y) << 16);
        o.y = f2bf(f0.z) | (f2bf(f0.w) << 16);
        o.z = f2bf(f1.x) | (f2bf(f1.y) << 16);
        o.w = f2bf(f1.z) | (f2bf(f1.w) << 16);
        ((uint4*)dst)[c] = o;
    }
}

// ---------------------------------------------------------------------------
// Prep 2: W1 [128][1024] fp32 -> bf16 in MFMA B-fragment order.
// chunk c = (nf*32 + ks)*64 + lane holds 8 bf16:
//   B[k][j] = W1[j][k], j = nf*16 + (lane&15), k = ks*32 + (lane>>4)*8 + b
// so the fused kernel's b-frag load is lane-contiguous 16B (fully coalesced).
// ---------------------------------------------------------------------------
__global__ __launch_bounds__(256) void prep_w1(const float* __restrict__ W1,
                                               unsigned int* __restrict__ dst) {
    int c = blockIdx.x * 256 + threadIdx.x;
    if (c >= 8 * 32 * 64) return;                    // 16384 chunks
    int l  = c & 63;
    int ks = (c >> 6) & 31;
    int nf = c >> 11;
    int o  = nf * 16 + (l & 15);
    int kb = ks * 32 + (l >> 4) * 8;
    float4 f0 = *(const float4*)(W1 + (size_t)o * 1024 + kb);
    float4 f1 = *(const float4*)(W1 + (size_t)o * 1024 + kb + 4);
    uint4 v;
    v.x = f2bf(f0.x) | (f2bf(f0.y) << 16);
    v.y = f2bf(f0.z) | (f2bf(f0.w) << 16);
    v.z = f2bf(f1.x) | (f2bf(f1.y) << 16);
    v.w = f2bf(f1.z) | (f2bf(f1.w) << 16);
    ((uint4*)dst)[c] = v;
}

// ---------------------------------------------------------------------------
// Fused: bag gather+sum+clip -> LDS bf16 x-tile (XOR-swizzled) -> MFMA layer1
// -> layer2 -> layer3+tanh. 512 blocks x 256 threads (4 waves), 32 pos/block.
//
// LDS map (73216 B -> 2 blocks/CU):
//   [0,65536)      phase 1: x tile, 32 rows x 2048 B (1024 bf16), swizzled
//                  phase 2: h1[32][132] f32 | w2[32][132] | h2[32][33] (38016 B)
//   [65536,73216)  sidx[64 bags][30] int (constant across phases)
//
// Swizzle (T2/G4): byte = row*2048 + (col ^ ((row&7)<<4)).  A-frag ds_read:
// 16 lanes share a 16B column over 16 rows -> unswizzled 16-way conflict;
// swizzled -> 8 slots x 2 rows = 2-way (free, m136). Same XOR on write side.
//
// MFMA: mfma_f32_16x16x32_bf16. A: row=lane&15, k=(lane>>4)*8+b;
// B: col=lane&15, same k (baked into w1f); C/D: col=lane&15,
// row=(lane>>4)*4+reg  [m89-verified]. Wave w: mf=0,1 x nf=2w,2w+1.
// ---------------------------------------------------------------------------
__global__ __launch_bounds__(256, 2) void nnue_fused(
    const int* __restrict__ stm_idx, const int* __restrict__ nstm_idx,
    const unsigned int* __restrict__ embbf,     // [NFEAT][512] bf16 (uint pairs)
    const unsigned int* __restrict__ w1f,       // frag-ordered bf16
    const float* __restrict__ b1,
    const float* __restrict__ W2, const float* __restrict__ b2,
    const float* __restrict__ W3, const float* __restrict__ b3,
    float* __restrict__ out)
{
    __shared__ __align__(16) char smem[73216];
    char* xb   = smem;
    int*  sidx = (int*)(smem + 65536);
    float* h1  = (float*)smem;                  // [32][132]
    float* w2  = (float*)smem + 32 * 132;       // [32][132]
    float* h2  = (float*)smem + 64 * 132;       // [32][33]

    const int t    = threadIdx.x;               // 0..255
    const int pblk = blockIdx.x * MT;
    const int w    = t >> 6;                    // wave 0..3
    const int lane = t & 63;

    // ---- stage bag indices: sidx[(p*2+side)*30 + l] ----
#pragma unroll
    for (int i = 0; i < 8; ++i) {
        int e = t + i * 256;                    // 0..2047
        if (e < 960) {
            int p = e / 30, l = e - p * 30;
            sidx[p * 60 + l] = stm_idx[(pblk + p) * 30 + l];
        } else if (e < 1920) {
            int e2 = e - 960;
            int p = e2 / 30, l = e2 - p * 30;
            sidx[p * 60 + 30 + l] = nstm_idx[(pblk + p) * 30 + l];
        }
    }
    __syncthreads();

    // ---- bag gather + sum + clip -> swizzled bf16 x tile ----
    // wave w handles bags 16w..16w+15; bag = p*2+side; lane covers 8 bf16 cols
#pragma unroll 1
    for (int i = 0; i < 16; ++i) {
        const int bag  = w * 16 + i;
        const int p    = bag >> 1;
        const int side = bag & 1;
        const int* ids = sidx + bag * 30;
        float ac[8];
#pragma unroll
        for (int j = 0; j < 8; ++j) ac[j] = 0.f;
#pragma unroll
        for (int l = 0; l < 30; ++l) {
            const uint4 v = *(const uint4*)(embbf + (size_t)ids[l] * 256 + (lane << 2));
            ac[0] += __uint_as_float(v.x << 16);
            ac[1] += __uint_as_float(v.x & 0xffff0000u);
            ac[2] += __uint_as_float(v.y << 16);
            ac[3] += __uint_as_float(v.y & 0xffff0000u);
            ac[4] += __uint_as_float(v.z << 16);
            ac[5] += __uint_as_float(v.z & 0xffff0000u);
            ac[6] += __uint_as_float(v.w << 16);
            ac[7] += __uint_as_float(v.w & 0xffff0000u);
        }
#pragma unroll
        for (int j = 0; j < 8; ++j) ac[j] = clip01(ac[j]);
        uint4 pk;
        pk.x = f2bf(ac[0]) | (f2bf(ac[1]) << 16);
        pk.y = f2bf(ac[2]) | (f2bf(ac[3]) << 16);
        pk.z = f2bf(ac[4]) | (f2bf(ac[5]) << 16);
        pk.w = f2bf(ac[6]) | (f2bf(ac[7]) << 16);
        const int col  = side * 1024 + lane * 16;
        const int addr = p * 2048 + (col ^ ((p & 7) << 4));
        *(uint4*)(xb + addr) = pk;
    }
    __syncthreads();

    // ---- layer1 GEMM via MFMA ----
    const int l15 = lane & 15, lg = lane >> 4, lq = lane & 7;
    f32x4 acc00 = {}, acc01 = {}, acc10 = {}, acc11 = {};
    const int arow0 = l15 * 2048;
    const int arow1 = arow0 + 16 * 2048;
    const bf16x8* w1v = (const bf16x8*)w1f;
#pragma unroll 4
    for (int ks = 0; ks < 32; ++ks) {
        const int acol = (ks * 64 + lg * 16) ^ (lq << 4);
        bf16x8 a0 = *(const bf16x8*)(xb + arow0 + acol);
        bf16x8 a1 = *(const bf16x8*)(xb + arow1 + acol);
        bf16x8 bf0 = w1v[((2 * w + 0) * 32 + ks) * 64 + lane];
        bf16x8 bf1 = w1v[((2 * w + 1) * 32 + ks) * 64 + lane];
        acc00 = __builtin_amdgcn_mfma_f32_16x16x32_bf16(a0, bf0, acc00, 0, 0, 0);
        acc01 = __builtin_amdgcn_mfma_f32_16x16x32_bf16(a0, bf1, acc01, 0, 0, 0);
        acc10 = __builtin_amdgcn_mfma_f32_16x16x32_bf16(a1, bf0, acc10, 0, 0, 0);
        acc11 = __builtin_amdgcn_mfma_f32_16x16x32_bf16(a1, bf1, acc11, 0, 0, 0);
    }
    __syncthreads();   // x tile dead; smem becomes h1/w2/h2

    // ---- epilogue: bias + clip -> h1[32][132] ----
    {
        const int o0 = (2 * w + 0) * 16 + l15;
        const int o1 = (2 * w + 1) * 16 + l15;
        const float bb0 = b1[o0], bb1 = b1[o1];
#pragma unroll
        for (int r = 0; r < 4; ++r) {
            int p0 = lg * 4 + r, p1 = 16 + lg * 4 + r;
            h1[p0 * 132 + o0] = clip01(acc00[r] + bb0);
            h1[p0 * 132 + o1] = clip01(acc01[r] + bb1);
            h1[p1 * 132 + o0] = clip01(acc10[r] + bb0);
            h1[p1 * 132 + o1] = clip01(acc11[r] + bb1);
        }
    }
    // stage W2 (32x128): 4096 floats, 16 per thread
#pragma unroll
    for (int i = 0; i < 16; ++i) {
        int f = t + i * 256;
        int o = f >> 7, k = f & 127;
        w2[o * 132 + k] = W2[o * 128 + k];
    }
    __syncthreads();

    // ---- layer2: 32 pos x 32 out; thread -> pos t>>3, 4 outputs ----
    {
        const int p2 = t >> 3;
        const int ob = (t & 7) * 4;
        float s[4];
#pragma unroll
        for (int jj = 0; jj < 4; ++jj) s[jj] = b2[ob + jj];
#pragma unroll
        for (int k4 = 0; k4 < 32; ++k4) {
            float4 h4 = *(const float4*)(h1 + p2 * 132 + k4 * 4);
#pragma unroll
            for (int jj = 0; jj < 4; ++jj) {
                float4 w4 = *(const float4*)(w2 + (ob + jj) * 132 + k4 * 4);
                s[jj] += h4.x * w4.x + h4.y * w4.y + h4.z * w4.z + h4.w * w4.w;
            }
        }
#pragma unroll
        for (int jj = 0; jj < 4; ++jj)
            h2[p2 * 33 + ob + jj] = clip01(s[jj]);
    }
    __syncthreads();

    // ---- layer3 + tanh ----
    if (t < MT) {
        float s = b3[0];
#pragma unroll
        for (int k = 0; k < 32; ++k) s += h2[t * 33 + k] * W3[k];
        out[pblk + t] = tanhf(s);
    }
}

// ---------------------------------------------------------------------------
extern "C" void kernel_launch(void* const* d_in, const int* in_sizes, int n_in,
                              void* d_out, int out_size, void* d_ws, size_t ws_size,
                              hipStream_t stream) {
    const int*   stm_idx  = (const int*)  d_in[0];
    const int*   nstm_idx = (const int*)  d_in[2];
    const float* emb      = (const float*)d_in[4];
    const float* W1       = (const float*)d_in[5];
    const float* b1       = (const float*)d_in[6];
    const float* W2       = (const float*)d_in[7];
    const float* b2       = (const float*)d_in[8];
    const float* W3       = (const float*)d_in[9];
    const float* b3       = (const float*)d_in[10];
    float*       out      = (float*)d_out;

    unsigned int* embbf = (unsigned int*)d_ws;                       // 41,943,040 B
    unsigned int* w1f   = (unsigned int*)((char*)d_ws + 41943040);   // 262,144 B

    cvt_emb<<<2048, 256, 0, stream>>>(emb, embbf);
    prep_w1<<<64, 256, 0, stream>>>(W1, w1f);
    nnue_fused<<<NPOS / MT, 256, 0, stream>>>(stm_idx, nstm_idx, embbf, w1f,
                                              b1, W2, b2, W3, b3, out);
}